// Round 3
// baseline (1582.872 us; speedup 1.0000x reference)
//
#include <hip/hip_runtime.h>

// ---------------------------------------------------------------------------
// StyleDecorator, round 3: bf16x3 (6-term) MFMA everywhere.
//  - LDS XOR-swizzle (kc ^ (row>>2)&3) kills 8-way ds_read_b128 conflicts
//    while preserving global_load_lds coalescing.
//  - cov K-split x4 (1024 blocks) + reduce: was 256-block latency-bound.
//  - NS iterations: register-direct GEMMs (no LDS/barriers, L2-resident
//    operands), Y/Z updates merged into one z=8 dispatch.
// ---------------------------------------------------------------------------

#define CH    512
#define NPIX  4096      // 64*64
#define HPAD  66
#define PPAD  4356      // 66*66
#define MROWS 4480      // padded row count for whitened-feature matrices
#define BANDW 2304      // S0T column band width (two bands cover 4416 cols)
#define BANDOFF 2112    // second band column offset
#define NS_ITERS 11

typedef unsigned short u16;
typedef __attribute__((ext_vector_type(8))) short short8;   // 8 bf16 (4 VGPRs)
typedef __attribute__((ext_vector_type(4))) float f32x4;    // MFMA C/D

__device__ __forceinline__ u16 bf16_rn(float x){
  union { float f; unsigned u; } v; v.f = x;
  unsigned u = v.u;
  return (u16)((u + 0x7FFFu + ((u >> 16) & 1u)) >> 16);
}
__device__ __forceinline__ float bf2f(u16 h){
  union { unsigned u; float f; } v; v.u = ((unsigned)h) << 16;
  return v.f;
}
__device__ __forceinline__ void split3(float x, u16& h, u16& m, u16& l){
  h = bf16_rn(x);
  float r1 = x - bf2f(h);
  m = bf16_rn(r1);
  l = bf16_rn(r1 - bf2f(m));
}
__device__ __forceinline__ void gll16(const void* g, void* l){
  __builtin_amdgcn_global_load_lds((const __attribute__((address_space(1))) unsigned*)g,
                                   (__attribute__((address_space(3))) unsigned*)l,
                                   16, 0, 0);
}
__device__ __forceinline__ f32x4 mfma_bf16(short8 a, short8 b, f32x4 c){
  return __builtin_amdgcn_mfma_f32_16x16x32_bf16(a, b, c, 0, 0, 0);
}

// ---------------------------------------------------------------------------
enum { M_COVP = 0, M_WHITEN = 3, M_S0 = 4, M_COLOR = 5 };

struct GP {
  const u16 *Ah, *Am, *Al, *Bh, *Bm, *Bl;
  size_t sAz, sBz;           // per-z strides (elements)
  float* Cf;
  u16 *Ch, *Cm, *Cl;
  size_t sCz;
  const float* scales;
  const float* meanv;
  int K;                     // row stride (elements)
  int Kit;                   // K iteration length for this launch
};

// C[m][n] = sum_k A[m][k]*B[n][k] with A,B stored as [row][K] bf16x3.
// 256 threads = 4 waves; TILE in {64,128}; wave computes (TILE/2)^2.
// LDS layout: per row, the four 16B k-chunks are stored at pos = kc ^ ((row>>2)&3)
// -> fragment ds_read_b128 is 2-way bank aliased (free), staging stays coalesced.
template<int TILE, int MODE>
__global__ __launch_bounds__(256, 2)
void gemm_sp(GP p){
  constexpr int MF = TILE / 32;
  const int z = blockIdx.z;
  const int zop = (MODE == M_COVP) ? (z >> 2) : z;
  const int kbase = (MODE == M_COVP) ? (z & 3) * p.Kit : 0;
  const u16* __restrict__ Ah = p.Ah + (size_t)zop * p.sAz;
  const u16* __restrict__ Am = p.Am + (size_t)zop * p.sAz;
  const u16* __restrict__ Al = p.Al + (size_t)zop * p.sAz;
  const u16* __restrict__ Bh = p.Bh + (size_t)zop * p.sBz;
  const u16* __restrict__ Bm = p.Bm + (size_t)zop * p.sBz;
  const u16* __restrict__ Bl = p.Bl + (size_t)zop * p.sBz;
  const int m0 = blockIdx.y * TILE, n0 = blockIdx.x * TILE;
  const int tid = threadIdx.x, ln = tid & 63, wv = tid >> 6;
  const int wm = (wv >> 1) * (TILE/2), wn = (wv & 1) * (TILE/2);
  __shared__ __align__(16) u16 sAh[TILE*32], sAm[TILE*32], sAl[TILE*32];
  __shared__ __align__(16) u16 sBh[TILE*32], sBm[TILE*32], sBl[TILE*32];
  f32x4 acc[MF][MF];
#pragma unroll
  for(int i=0;i<MF;++i)
#pragma unroll
    for(int j=0;j<MF;++j) acc[i][j] = (f32x4)0.0f;
  const int K = p.K;
  for(int kk = 0; kk < p.Kit; kk += 32){
    const int k0 = kbase + kk;
#pragma unroll
    for(int s = tid; s < TILE*4; s += 256){      // 16B slots, 4 per row
      const int row = s >> 2, pos = s & 3;
      const int kc = pos ^ ((row >> 2) & 3);     // XOR swizzle
      const size_t ga = (size_t)(m0 + row) * K + k0 + kc*8;
      const size_t gb = (size_t)(n0 + row) * K + k0 + kc*8;
      gll16(Ah + ga, sAh + s*8);
      gll16(Am + ga, sAm + s*8);
      gll16(Al + ga, sAl + s*8);
      gll16(Bh + gb, sBh + s*8);
      gll16(Bm + gb, sBm + s*8);
      gll16(Bl + gb, sBl + s*8);
    }
    __syncthreads();
    short8 ah[MF], am[MF], al[MF], bh[MF], bm[MF], bl[MF];
#pragma unroll
    for(int i=0;i<MF;++i){
      const int ra = wm + i*16 + (ln & 15);
      const int rb = wn + i*16 + (ln & 15);
      const int pa = (ln >> 4) ^ ((ra >> 2) & 3);
      const int pb = (ln >> 4) ^ ((rb >> 2) & 3);
      const int ofa = ra*32 + pa*8;
      const int ofb = rb*32 + pb*8;
      ah[i] = *(const short8*)(sAh + ofa);
      am[i] = *(const short8*)(sAm + ofa);
      al[i] = *(const short8*)(sAl + ofa);
      bh[i] = *(const short8*)(sBh + ofb);
      bm[i] = *(const short8*)(sBm + ofb);
      bl[i] = *(const short8*)(sBl + ofb);
    }
#pragma unroll
    for(int i=0;i<MF;++i)
#pragma unroll
      for(int j=0;j<MF;++j){
        acc[i][j] = mfma_bf16(ah[i], bh[j], acc[i][j]);
        acc[i][j] = mfma_bf16(ah[i], bm[j], acc[i][j]);
        acc[i][j] = mfma_bf16(am[i], bh[j], acc[i][j]);
        acc[i][j] = mfma_bf16(am[i], bm[j], acc[i][j]);
        acc[i][j] = mfma_bf16(ah[i], bl[j], acc[i][j]);
        acc[i][j] = mfma_bf16(al[i], bh[j], acc[i][j]);
      }
    __syncthreads();
  }
  // epilogue: C/D layout col=lane&15, row=(lane>>4)*4+reg
#pragma unroll
  for(int i=0;i<MF;++i)
#pragma unroll
    for(int j=0;j<MF;++j)
#pragma unroll
      for(int r=0;r<4;++r){
        const int m = m0 + wm + i*16 + (ln >> 4)*4 + r;
        const int n = n0 + wn + j*16 + (ln & 15);
        float v = acc[i][j][r];
        if constexpr (MODE == M_COVP){
          p.Cf[(size_t)z * p.sCz + (size_t)m * CH + n] = v;   // raw partial
        } else if constexpr (MODE == M_WHITEN){
          v *= p.scales[z*4 + 3];                 // rsqrt(c)
          const int prow = ((m >> 6) + 1)*HPAD + (m & 63) + 1;
          u16 h, mm2, l; split3(v, h, mm2, l);
          const size_t o = (size_t)z*p.sCz + (size_t)prow*CH + n;
          p.Ch[o] = h; p.Cm[o] = mm2; p.Cl[o] = l;
        } else if constexpr (MODE == M_S0){
          p.Cf[(size_t)m * BANDW + n] = v;
        } else {                                  // M_COLOR
          const float sc = p.scales[(2+z)*4 + 2]; // sqrt(c)
          const float mu = p.meanv[(2+z)*CH + m];
          p.Cf[(size_t)z*p.sCz + (size_t)m*NPIX + n] = v*sc + mu;
        }
      }
}

// ---------------- cov reduce: sum 4 K-chunks, scale 1/4095 ------------------
__global__ __launch_bounds__(256)
void cov_reduce_kernel(const float* __restrict__ covp, float* __restrict__ cov){
  size_t t = (size_t)blockIdx.x * 256 + threadIdx.x;   // 4*512*512
  int z = (int)(t >> 18);
  size_t e = t & 262143;
  float s = 0.f;
#pragma unroll
  for(int c = 0; c < 4; ++c) s += covp[((size_t)(z*4 + c) << 18) + e];
  cov[t] = s * (1.0f / 4095.0f);
}

// ---------------- NS register-direct GEMMs (no LDS, no barriers) ------------
// Wave computes 32x32; fragments loaded straight from global (L2-resident).
__global__ __launch_bounds__(256)
void ns_t_kernel(const u16* __restrict__ Zh, const u16* __restrict__ Zm, const u16* __restrict__ Zl,
                 const u16* __restrict__ Yh, const u16* __restrict__ Ym, const u16* __restrict__ Yl,
                 u16* __restrict__ Th_, u16* __restrict__ Tm_, u16* __restrict__ Tl_){
  const size_t zb = (size_t)blockIdx.z * CH * CH;
  const int ln = threadIdx.x & 63, wv = threadIdx.x >> 6;
  const int m0 = blockIdx.y * 64 + (wv >> 1) * 32;
  const int n0 = blockIdx.x * 64 + (wv & 1) * 32;
  const int r = ln & 15, q = ln >> 4;
  const u16 *A0 = Zh + zb, *A1 = Zm + zb, *A2 = Zl + zb;
  const u16 *B0 = Yh + zb, *B1 = Ym + zb, *B2 = Yl + zb;
  f32x4 acc[2][2];
#pragma unroll
  for(int i=0;i<2;++i)
#pragma unroll
    for(int j=0;j<2;++j) acc[i][j] = (f32x4)0.0f;
#pragma unroll 2
  for(int k0 = 0; k0 < CH; k0 += 32){
    short8 ah[2], am[2], al[2], bh[2], bm[2], bl[2];
#pragma unroll
    for(int i = 0; i < 2; ++i){
      const size_t ao = (size_t)(m0 + i*16 + r) * CH + k0 + q*8;
      const size_t bo = (size_t)(n0 + i*16 + r) * CH + k0 + q*8;
      ah[i] = *(const short8*)(A0 + ao); am[i] = *(const short8*)(A1 + ao); al[i] = *(const short8*)(A2 + ao);
      bh[i] = *(const short8*)(B0 + bo); bm[i] = *(const short8*)(B1 + bo); bl[i] = *(const short8*)(B2 + bo);
    }
#pragma unroll
    for(int i=0;i<2;++i)
#pragma unroll
      for(int j=0;j<2;++j){
        acc[i][j] = mfma_bf16(ah[i], bh[j], acc[i][j]);
        acc[i][j] = mfma_bf16(ah[i], bm[j], acc[i][j]);
        acc[i][j] = mfma_bf16(am[i], bh[j], acc[i][j]);
        acc[i][j] = mfma_bf16(am[i], bm[j], acc[i][j]);
        acc[i][j] = mfma_bf16(ah[i], bl[j], acc[i][j]);
        acc[i][j] = mfma_bf16(al[i], bh[j], acc[i][j]);
      }
  }
#pragma unroll
  for(int i=0;i<2;++i)
#pragma unroll
    for(int j=0;j<2;++j)
#pragma unroll
      for(int rr=0;rr<4;++rr){
        const int m = m0 + i*16 + q*4 + rr;
        const int n = n0 + j*16 + r;
        float v = -0.5f*acc[i][j][rr] + ((m == n) ? 1.5f : 0.0f);
        u16 h, mm2, l; split3(v, h, mm2, l);
        const size_t o = zb + (size_t)m*CH + n;
        Th_[o] = h; Tm_[o] = mm2; Tl_[o] = l;
      }
}

struct NUP {
  const u16 *Yh,*Ym,*Yl, *Zh,*Zm,*Zl, *Th,*Tm,*Tl;
  u16 *Ynh,*Ynm,*Ynl, *Znh,*Znm,*Znl;
};
__global__ __launch_bounds__(256)
void ns_upd_kernel(NUP p){
  const int z = blockIdx.z;                 // 0..3: Yn=Y*T ; 4..7: Zn=T*Z
  const size_t zb = (size_t)(z & 3) * CH * CH;
  const bool first = z < 4;
  const u16 *A0, *A1, *A2, *B0, *B1, *B2;
  u16 *C0, *C1, *C2;
  if(first){ A0=p.Yh+zb; A1=p.Ym+zb; A2=p.Yl+zb; B0=p.Th+zb; B1=p.Tm+zb; B2=p.Tl+zb;
             C0=p.Ynh;   C1=p.Ynm;   C2=p.Ynl; }
  else     { A0=p.Th+zb; A1=p.Tm+zb; A2=p.Tl+zb; B0=p.Zh+zb; B1=p.Zm+zb; B2=p.Zl+zb;
             C0=p.Znh;   C1=p.Znm;   C2=p.Znl; }
  const int ln = threadIdx.x & 63, wv = threadIdx.x >> 6;
  const int m0 = blockIdx.y * 64 + (wv >> 1) * 32;
  const int n0 = blockIdx.x * 64 + (wv & 1) * 32;
  const int r = ln & 15, q = ln >> 4;
  f32x4 acc[2][2];
#pragma unroll
  for(int i=0;i<2;++i)
#pragma unroll
    for(int j=0;j<2;++j) acc[i][j] = (f32x4)0.0f;
#pragma unroll 2
  for(int k0 = 0; k0 < CH; k0 += 32){
    short8 ah[2], am[2], al[2], bh[2], bm[2], bl[2];
#pragma unroll
    for(int i = 0; i < 2; ++i){
      const size_t ao = (size_t)(m0 + i*16 + r) * CH + k0 + q*8;
      const size_t bo = (size_t)(n0 + i*16 + r) * CH + k0 + q*8;
      ah[i] = *(const short8*)(A0 + ao); am[i] = *(const short8*)(A1 + ao); al[i] = *(const short8*)(A2 + ao);
      bh[i] = *(const short8*)(B0 + bo); bm[i] = *(const short8*)(B1 + bo); bl[i] = *(const short8*)(B2 + bo);
    }
#pragma unroll
    for(int i=0;i<2;++i)
#pragma unroll
      for(int j=0;j<2;++j){
        acc[i][j] = mfma_bf16(ah[i], bh[j], acc[i][j]);
        acc[i][j] = mfma_bf16(ah[i], bm[j], acc[i][j]);
        acc[i][j] = mfma_bf16(am[i], bh[j], acc[i][j]);
        acc[i][j] = mfma_bf16(am[i], bm[j], acc[i][j]);
        acc[i][j] = mfma_bf16(ah[i], bl[j], acc[i][j]);
        acc[i][j] = mfma_bf16(al[i], bh[j], acc[i][j]);
      }
  }
#pragma unroll
  for(int i=0;i<2;++i)
#pragma unroll
    for(int j=0;j<2;++j)
#pragma unroll
      for(int rr=0;rr<4;++rr){
        const int m = m0 + i*16 + q*4 + rr;
        const int n = n0 + j*16 + r;
        u16 h, mm2, l; split3(acc[i][j][rr], h, mm2, l);
        const size_t o = zb + (size_t)m*CH + n;
        C0[o] = h; C1[o] = mm2; C2[o] = l;
      }
}

// ---------------- per-(matrix,channel) mean over 4096 pixels ----------------
__global__ __launch_bounds__(256)
void mean_kernel(const float* __restrict__ content, const float* __restrict__ style,
                 float* __restrict__ meanv){
  int mm = blockIdx.x;           // 0..2047
  int z = mm >> 9, c = mm & 511;
  const float* X = ((z < 2) ? content + (size_t)z * CH * NPIX
                            : style   + (size_t)(z - 2) * CH * NPIX) + (size_t)c * NPIX;
  float s = 0.f;
  for(int i = threadIdx.x; i < NPIX; i += 256) s += X[i];
  __shared__ float red[256];
  red[threadIdx.x] = s; __syncthreads();
  for(int w = 128; w > 0; w >>= 1){
    if(threadIdx.x < w) red[threadIdx.x] += red[threadIdx.x + w];
    __syncthreads();
  }
  if(threadIdx.x == 0) meanv[mm] = red[0] * (1.0f / NPIX);
}

// ------- center + bf16x3 split, emit both [c][pix] and [pix][c] layouts -----
__global__ __launch_bounds__(256)
void center_split_kernel(const float* __restrict__ content, const float* __restrict__ style,
                         const float* __restrict__ meanv,
                         u16* __restrict__ Xch, u16* __restrict__ Xcm, u16* __restrict__ Xcl,
                         u16* __restrict__ XcTh, u16* __restrict__ XcTm, u16* __restrict__ XcTl){
  int z = blockIdx.z;
  const float* X = (z < 2) ? content + (size_t)z * CH * NPIX
                           : style   + (size_t)(z - 2) * CH * NPIX;
  int p0 = blockIdx.x * 64, c0 = blockIdx.y * 64;
  __shared__ float T[64][65];
  int col = threadIdx.x & 63, rq = threadIdx.x >> 6;
#pragma unroll
  for(int i = 0; i < 16; ++i){
    int r = i*4 + rq;
    int c = c0 + r;
    float v = X[(size_t)c * NPIX + p0 + col] - meanv[z*CH + c];
    u16 h, m, l; split3(v, h, m, l);
    size_t o = (size_t)(z*CH + c) * NPIX + p0 + col;
    Xch[o] = h; Xcm[o] = m; Xcl[o] = l;
    T[col][r] = v;
  }
  __syncthreads();
#pragma unroll
  for(int i = 0; i < 16; ++i){
    int r = i*4 + rq;                 // pixel-in-tile
    float v = T[r][col];
    u16 h, m, l; split3(v, h, m, l);
    size_t o = (size_t)(z*NPIX + p0 + r) * CH + c0 + col;
    XcTh[o] = h; XcTm[o] = m; XcTl[o] = l;
  }
}

// ---------------- scale[z] = {c, 1/c, sqrt(c), rsqrt(c)} --------------------
__global__ __launch_bounds__(256)
void scale_kernel(const float* __restrict__ cov, float* __restrict__ scales){
  int z = blockIdx.x;
  const float* C = cov + (size_t)z * CH * CH;
  float mx = 0.f;
  for(int r = threadIdx.x; r < CH; r += 256){
    float s = 0.f;
    for(int c2 = 0; c2 < CH; ++c2) s += fabsf(C[(size_t)r * CH + c2]);
    mx = fmaxf(mx, s);
  }
  __shared__ float red[256];
  red[threadIdx.x] = mx; __syncthreads();
  for(int w = 128; w > 0; w >>= 1){
    if(threadIdx.x < w) red[threadIdx.x] = fmaxf(red[threadIdx.x], red[threadIdx.x + w]);
    __syncthreads();
  }
  if(threadIdx.x == 0){
    float c = red[0];
    scales[z*4+0] = c;
    scales[z*4+1] = 1.0f / c;
    scales[z*4+2] = sqrtf(c);
    scales[z*4+3] = rsqrtf(c);
  }
}

// ---------------- Y0 = cov/c (x3), Z0 = I (x3) ------------------------------
__global__ __launch_bounds__(256)
void ns_init_kernel(const float* __restrict__ cov, const float* __restrict__ scales,
                    u16* Yh, u16* Ym, u16* Yl, u16* Zh, u16* Zm, u16* Zl){
  size_t t = (size_t)blockIdx.x * 256 + threadIdx.x;   // 4*512*512
  int z = (int)(t >> 18);
  size_t e = t & 262143;
  int row = (int)(e >> 9), col = (int)(e & 511);
  float v = cov[t] * scales[z*4+1];
  u16 h, m, l; split3(v, h, m, l);
  Yh[t] = h; Ym[t] = m; Yl[t] = l;
  Zh[t] = (row == col) ? (u16)0x3F80 : (u16)0;
  Zm[t] = 0; Zl[t] = 0;
}

// ---------------- cn2[p'] = ||whitened style column||^2 ---------------------
__global__ __launch_bounds__(256)
void cn2_kernel(const u16* __restrict__ Wh, const u16* __restrict__ Wm,
                const u16* __restrict__ Wl, float* __restrict__ cn2){
  int b = blockIdx.y;
  int row = blockIdx.x * 16 + (threadIdx.x >> 4);
  int t = threadIdx.x & 15;
  float s = 0.f;
  if(row < PPAD){
    size_t base = ((size_t)(2 + b) * MROWS + row) * CH;
    for(int ch = t; ch < 64; ch += 16){
      uint4 hv = *(const uint4*)(Wh + base + ch*8);
      uint4 mv = *(const uint4*)(Wm + base + ch*8);
      uint4 lv = *(const uint4*)(Wl + base + ch*8);
      const unsigned* hw = (const unsigned*)&hv;
      const unsigned* mw = (const unsigned*)&mv;
      const unsigned* lw = (const unsigned*)&lv;
#pragma unroll
      for(int w = 0; w < 4; ++w){
        float v0 = bf2f((u16)(hw[w] & 0xFFFF)) + bf2f((u16)(mw[w] & 0xFFFF)) + bf2f((u16)(lw[w] & 0xFFFF));
        float v1 = bf2f((u16)(hw[w] >> 16))    + bf2f((u16)(mw[w] >> 16))    + bf2f((u16)(lw[w] >> 16));
        s = fmaf(v0, v0, s); s = fmaf(v1, v1, s);
      }
    }
  }
  for(int off = 8; off; off >>= 1) s += __shfl_down(s, off, 16);
  if(t == 0 && row < PPAD) cn2[b*PPAD + row] = s;
}

// ---------------- rnorm[p] = 1/(sqrt(sum of 9 taps)+1e-5) -------------------
__global__ __launch_bounds__(256)
void rnorm_kernel(const float* __restrict__ cn2, float* __restrict__ rnorm){
  int b = blockIdx.y;
  int p = blockIdx.x * 256 + threadIdx.x;   // 0..4095
  int py = p >> 6, px = p & 63;
  const float* c2 = cn2 + (size_t)b * PPAD + (size_t)py * HPAD + px;
  float s = 0.f;
#pragma unroll
  for(int i = 0; i < 3; ++i)
#pragma unroll
    for(int j = 0; j < 3; ++j) s += c2[i * HPAD + j];
  rnorm[b * 4096 + p] = 1.0f / (sqrtf(s) + 1e-5f);
}

// ---------------- per-p-chunk argmax of 9-tap stencil score (banded) --------
__global__ __launch_bounds__(256)
void score_partial_kernel(const float* __restrict__ S0T, const float* __restrict__ rnorm,
                          float* __restrict__ pmax, int* __restrict__ pidx,
                          int b, int qy0, int colbase){
  int q = qy0*64 + blockIdx.y * 256 + threadIdx.x;
  int chunk = blockIdx.x;
  int qy = q >> 6, qx = q & 63;
  int qcol = qy * HPAD + qx - colbase;
  const float* rn = rnorm + b * 4096;
  float best = -1e30f; int bestp = 0;
  for(int p = chunk * 64; p < chunk * 64 + 64; ++p){
    int py = p >> 6, px = p & 63;
    const float* base = S0T + (size_t)(py * HPAD + px) * BANDW + qcol;
    float s = 0.f;
#pragma unroll
    for(int i = 0; i < 3; ++i)
#pragma unroll
      for(int j = 0; j < 3; ++j)
        s += base[(size_t)(i * HPAD + j) * (BANDW + 1)];
    s *= rn[p];
    if(s > best){ best = s; bestp = p; }
  }
  pmax[(size_t)chunk * 4096 + q] = best;
  pidx[(size_t)chunk * 4096 + q] = bestp;
}

__global__ __launch_bounds__(256)
void argmax_merge_kernel(const float* __restrict__ pmax, const int* __restrict__ pidx,
                         int* __restrict__ idx, int b){
  int q = blockIdx.x * 256 + threadIdx.x;
  float best = -1e30f; int bp = 0;
  for(int ch = 0; ch < 64; ++ch){
    float v = pmax[(size_t)ch * 4096 + q];
    if(v > best){ best = v; bp = pidx[(size_t)ch * 4096 + q]; }
  }
  idx[b * 4096 + q] = bp;
}

// ---------------- gather matched patches, overlap-add, write RT x3 ----------
__global__ __launch_bounds__(256)
void gather_kernel(const u16* __restrict__ Wh, const u16* __restrict__ Wm,
                   const u16* __restrict__ Wl, const int* __restrict__ idx,
                   u16* __restrict__ RTh, u16* __restrict__ RTm, u16* __restrict__ RTl){
  int g = blockIdx.x * 256 + threadIdx.x;   // 2*4096*64
  int cg = g & 63;
  int pix = (g >> 6) & 4095;
  int b = g >> 18;
  int y = pix >> 6, x = pix & 63;
  const int* idxb = idx + b * 4096;
  size_t matbase = (size_t)(2 + b) * MROWS * CH;
  float a8[8] = {0,0,0,0,0,0,0,0};
  int cnt = 0;
#pragma unroll
  for(int i = 0; i < 3; ++i){
    int qy = y + 1 - i;
    if((unsigned)qy >= 64u) continue;
#pragma unroll
    for(int j = 0; j < 3; ++j){
      int qx = x + 1 - j;
      if((unsigned)qx >= 64u) continue;
      int p = idxb[qy * 64 + qx];
      int row = ((p >> 6) + i) * HPAD + (p & 63) + j;
      size_t off = matbase + (size_t)row * CH + cg * 8;
      uint4 hv = *(const uint4*)(Wh + off);
      uint4 mv = *(const uint4*)(Wm + off);
      uint4 lv = *(const uint4*)(Wl + off);
      const unsigned* hw = (const unsigned*)&hv;
      const unsigned* mw = (const unsigned*)&mv;
      const unsigned* lw = (const unsigned*)&lv;
#pragma unroll
      for(int w = 0; w < 4; ++w){
        a8[2*w]   += bf2f((u16)(hw[w] & 0xFFFF)) + bf2f((u16)(mw[w] & 0xFFFF)) + bf2f((u16)(lw[w] & 0xFFFF));
        a8[2*w+1] += bf2f((u16)(hw[w] >> 16))    + bf2f((u16)(mw[w] >> 16))    + bf2f((u16)(lw[w] >> 16));
      }
      ++cnt;
    }
  }
  float inv = 1.0f / (float)cnt;
  u16 oh[8], om[8], ol[8];
#pragma unroll
  for(int k = 0; k < 8; ++k){
    float v = a8[k] * inv;
    split3(v, oh[k], om[k], ol[k]);
  }
  size_t ro = ((size_t)(b * 4096 + pix)) * CH + cg * 8;
  *(uint4*)(RTh + ro) = *(const uint4*)oh;
  *(uint4*)(RTm + ro) = *(const uint4*)om;
  *(uint4*)(RTl + ro) = *(const uint4*)ol;
}

// ---------------------------------------------------------------------------
extern "C" void kernel_launch(void* const* d_in, const int* in_sizes, int n_in,
                              void* d_out, int out_size, void* d_ws, size_t ws_size,
                              hipStream_t stream){
  (void)in_sizes; (void)n_in; (void)out_size; (void)ws_size;
  const float* content = (const float*)d_in[0];
  const float* style   = (const float*)d_in[1];
  float* out = (float*)d_out;

  char* base = (char*)d_ws;
  size_t off = 0;
  auto take = [&](size_t nbytes) -> char* {
    char* p = base + off;
    off = (off + nbytes + 255) & ~(size_t)255;
    return p;
  };
  const size_t MAT = (size_t)CH*CH*2;            // 512x512 bf16 bytes
  const size_t FEAT = (size_t)CH*NPIX*2;         // 512x4096 bf16 bytes
  const size_t WMAT = (size_t)MROWS*CH*2;        // 4480x512 bf16 bytes

  float* meanv  = (float*)take((size_t)4*CH*sizeof(float));
  float* scales = (float*)take(256);
  float* cov    = (float*)take((size_t)4*CH*CH*sizeof(float));
  u16 *Yh=(u16*)take(4*MAT), *Ym=(u16*)take(4*MAT), *Yl=(u16*)take(4*MAT);
  u16 *Zh=(u16*)take(4*MAT), *Zm=(u16*)take(4*MAT), *Zl=(u16*)take(4*MAT);
  u16 *Th=(u16*)take(4*MAT), *Tm=(u16*)take(4*MAT), *Tl=(u16*)take(4*MAT);
  u16 *Ynh=(u16*)take(4*MAT), *Ynm=(u16*)take(4*MAT), *Ynl=(u16*)take(4*MAT);
  u16 *Znh=(u16*)take(4*MAT), *Znm=(u16*)take(4*MAT), *Znl=(u16*)take(4*MAT);
  // cov K-split partials (16 MB) alias the NS temp region (dead at cov time):
  // Th..Znm are 8 contiguous 2MB arrays (all sizes are 256B multiples).
  float* covp = (float*)Th;
  // P1: Xc x3 (center->cov)  then  W x3 (post-NS -> end)
  char* P1 = take(3*(size_t)4*WMAT);
  u16 *Xch=(u16*)P1, *Xcm=(u16*)(P1+4*FEAT), *Xcl=(u16*)(P1+8*FEAT);
  u16 *Wh=(u16*)P1, *Wm=(u16*)(P1+4*WMAT), *Wl=(u16*)(P1+8*WMAT);
  // P0: XcT x3 (center->whiten), then S0T band, then RT x3
  char* P0 = take(3*(size_t)4*FEAT);
  u16 *XcTh=(u16*)P0, *XcTm=(u16*)(P0+4*FEAT), *XcTl=(u16*)(P0+8*FEAT);
  float* S0T = (float*)P0;
  u16 *RTh=(u16*)P0, *RTm=(u16*)(P0+2*FEAT), *RTl=(u16*)(P0+4*FEAT);
  float* cn2    = (float*)take((size_t)2*PPAD*sizeof(float));
  float* rnormb = (float*)take((size_t)2*4096*sizeof(float));
  float* pmax   = (float*)take((size_t)64*4096*sizeof(float));
  int*   pidx   = (int*)  take((size_t)64*4096*sizeof(int));
  int*   idxb   = (int*)  take((size_t)2*4096*sizeof(int));

  mean_kernel<<<2048, 256, 0, stream>>>(content, style, meanv);
  center_split_kernel<<<dim3(64, 8, 4), 256, 0, stream>>>(content, style, meanv,
                                                          Xch, Xcm, Xcl, XcTh, XcTm, XcTl);
  // cov partials: z = matrix*4 + K-chunk, 1024 blocks
  {
    GP g{}; g.Ah=Xch; g.Am=Xcm; g.Al=Xcl; g.Bh=Xch; g.Bm=Xcm; g.Bl=Xcl;
    g.sAz = g.sBz = (size_t)CH*NPIX; g.Cf = covp; g.sCz = (size_t)CH*CH;
    g.K = NPIX; g.Kit = 1024;
    gemm_sp<64, M_COVP><<<dim3(8, 8, 16), 256, 0, stream>>>(g);
  }
  cov_reduce_kernel<<<4096, 256, 0, stream>>>(covp, cov);
  scale_kernel<<<4, 256, 0, stream>>>(cov, scales);
  ns_init_kernel<<<4096, 256, 0, stream>>>(cov, scales, Yh, Ym, Yl, Zh, Zm, Zl);

  u16 *Ach[3]={Yh,Ym,Yl}, *Bch[3]={Zh,Zm,Zl}, *An[3]={Ynh,Ynm,Ynl}, *Bn[3]={Znh,Znm,Znl};
  for(int it = 0; it < NS_ITERS; ++it){
    ns_t_kernel<<<dim3(8, 8, 4), 256, 0, stream>>>(Bch[0], Bch[1], Bch[2],
                                                   Ach[0], Ach[1], Ach[2],
                                                   Th, Tm, Tl);
    NUP u{Ach[0],Ach[1],Ach[2], Bch[0],Bch[1],Bch[2], Th,Tm,Tl,
          An[0],An[1],An[2], Bn[0],Bn[1],Bn[2]};
    ns_upd_kernel<<<dim3(8, 8, 8), 256, 0, stream>>>(u);
    for(int c = 0; c < 3; ++c){ u16* tmp=Ach[c]; Ach[c]=An[c]; An[c]=tmp;
                                tmp=Bch[c]; Bch[c]=Bn[c]; Bn[c]=tmp; }
  }

  // W (padded, zero borders) -- Xc region is dead now; Wh/Wm/Wl alias it
  hipMemsetAsync(Wh, 0, 4*WMAT, stream);
  hipMemsetAsync(Wm, 0, 4*WMAT, stream);
  hipMemsetAsync(Wl, 0, 4*WMAT, stream);
  // W[pix][c] = XcT * Z  (Z symmetric), scaled by rsqrt(c)
  {
    GP w{}; w.Ah=XcTh; w.Am=XcTm; w.Al=XcTl; w.sAz=(size_t)NPIX*CH;
    w.Bh=Bch[0]; w.Bm=Bch[1]; w.Bl=Bch[2]; w.sBz=(size_t)CH*CH;
    w.Ch=Wh; w.Cm=Wm; w.Cl=Wl; w.sCz=(size_t)MROWS*CH; w.scales=scales;
    w.K = CH; w.Kit = CH;
    gemm_sp<128, M_WHITEN><<<dim3(4, 32, 4), 256, 0, stream>>>(w);
  }
  cn2_kernel<<<dim3(273, 2), 256, 0, stream>>>(Wh, Wm, Wl, cn2);
  rnorm_kernel<<<dim3(16, 2), 256, 0, stream>>>(cn2, rnormb);

  for(int b = 0; b < 2; ++b){
    for(int band = 0; band < 2; ++band){
      GP s{};
      s.Ah = Wh + (size_t)(2+b)*MROWS*CH; s.Am = Wm + (size_t)(2+b)*MROWS*CH; s.Al = Wl + (size_t)(2+b)*MROWS*CH;
      size_t bo = (size_t)b*MROWS*CH + (size_t)(band ? BANDOFF : 0)*CH;
      s.Bh = Wh + bo; s.Bm = Wm + bo; s.Bl = Wl + bo;
      s.sAz = s.sBz = 0; s.Cf = S0T; s.sCz = 0; s.K = CH; s.Kit = CH;
      gemm_sp<128, M_S0><<<dim3(BANDW/128, MROWS/128, 1), 256, 0, stream>>>(s);
      score_partial_kernel<<<dim3(64, 8), 256, 0, stream>>>(S0T, rnormb, pmax, pidx,
                                                            b, band ? 32 : 0,
                                                            band ? BANDOFF : 0);
    }
    argmax_merge_kernel<<<16, 256, 0, stream>>>(pmax, pidx, idxb, b);
  }

  gather_kernel<<<2048, 256, 0, stream>>>(Wh, Wm, Wl, idxb, RTh, RTm, RTl);
  // out = Ys * R * sqrt(c) + mu   (Ys symmetric)
  {
    GP c{}; c.Ah = Ach[0] + 2*(size_t)CH*CH; c.Am = Ach[1] + 2*(size_t)CH*CH; c.Al = Ach[2] + 2*(size_t)CH*CH;
    c.sAz = (size_t)CH*CH;
    c.Bh = RTh; c.Bm = RTm; c.Bl = RTl; c.sBz = (size_t)NPIX*CH;
    c.Cf = out; c.sCz = (size_t)CH*NPIX; c.scales = scales; c.meanv = meanv;
    c.K = CH; c.Kit = CH;
    gemm_sp<128, M_COLOR><<<dim3(32, 4, 2), 256, 0, stream>>>(c);
  }
}